// Round 9
// baseline (139.130 us; speedup 1.0000x reference)
//
#include <hip/hip_runtime.h>

// DeformUnfold R8: R5 pipeline (ROWS=23/MARG=9, 1 barrier/iter, nt stores)
// + 3 blocks/CU: launch_bounds(512,6) (VGPR cap 85), meta packed to 45 regs
// (at|ab in one int), CPB 32->16 so grid=1024 supplies >=3 blocks/CU.
// Block = (batch, 4-row quad, 16-ch group), 512 threads, 1 sp each.
// Slow path probability ~1e-15 (MARG=9) - effectively never taken.

constexpr int Bc = 8;
constexpr int Cc = 64;
constexpr int Hc = 128;
constexpr int Wc = 128;
constexpr int Kc = 9;
constexpr int HWc = 16384;
constexpr int ORc = 4;                // output rows per block
constexpr int ROWS = 23;              // staged window rows
constexpr int TILE = ROWS * Wc;       // 2944 floats (11.5 KB)
constexpr int TILE4 = TILE / 4;       // 736 float4
constexpr int CPB = 16;               // channels per block
constexpr int PAIRS = CPB / 2;        // 8 iterations
constexpr int MARG = 9;
constexpr int NT = 512;

__global__ __launch_bounds__(NT, 6) void deform_lds6(
    const float* __restrict__ x,
    const float* __restrict__ offset,
    float* __restrict__ out)
{
    __shared__ float buf[2][2][TILE];     // 46 KB -> 3 blocks/CU LDS-wise

    // XCD swizzle: batch b -> XCD b; h fastest so same-window blocks adjacent
    int wg = (int)((blockIdx.x & 7) * 128 + (blockIdx.x >> 3));
    int h  = wg & 3;                  // channel quarter
    int rq = (wg >> 2) & 31;          // row quad
    int b  = wg >> 7;

    int r0  = rq * ORc;
    int w0  = min(max(r0 - MARG, 0), Hc - ROWS);
    int tid = (int)threadIdx.x;
    int ho  = r0 + (tid >> 7);
    int wo  = tid & 127;
    int spg = r0 * Wc + tid;
    int ch0 = h * CPB;

    const float* offb = offset + (size_t)b * (2 * Kc) * HWc + spg;

    // ---- per-thread sampling meta: 9 packed addrs + 36 weight regs ----
    int   am[Kc];                     // at in [11:0], ab in [27:16]
    float wA[Kc], wB[Kc], wyt[Kc], wyb[Kc];
    bool allok = true;
#pragma unroll
    for (int k = 0; k < Kc; ++k) {
        float offy = offb[(size_t)(2 * k) * HWc];
        float offx = offb[(size_t)(2 * k + 1) * HWc];
        float py = (float)(k / 3 + ho - 1) + offy;
        float px = (float)(k % 3 + wo - 1) + offx;
        float y0f = floorf(py), x0f = floorf(px);
        float ly = py - y0f, lx = px - x0f;
        float hy = 1.0f - ly, hx = 1.0f - lx;
        int y0 = (int)y0f, x0 = (int)x0f;
        int y1 = y0 + 1;

        bool vy0 = (unsigned)y0 < (unsigned)Hc;
        bool vy1 = (unsigned)y1 < (unsigned)Hc;
        wyt[k] = hy * (vy0 ? 1.0f : 0.0f);
        wyb[k] = ly * (vy1 ? 1.0f : 0.0f);

        int xb = min(max(x0, 0), Wc - 2);
        bool n  = (x0 == xb);
        bool lo = (x0 + 1 == xb);
        bool hi = (x0 == xb + 1);
        wA[k] = (n ? hx : 0.0f) + (lo ? lx : 0.0f);
        wB[k] = (n ? lx : 0.0f) + (hi ? hx : 0.0f);

        int y0c = min(max(y0, 0), Hc - 1);
        int y1c = min(max(y1, 0), Hc - 1);
        allok = allok & (y0c >= w0) & (y0c < w0 + ROWS)
                      & (y1c >= w0) & (y1c < w0 + ROWS);
        int at = (y0c - w0) * Wc + xb;
        int ab = (y1c - w0) * Wc + xb;
        am[k] = at | (ab << 16);
    }

    const float* xw = x + ((size_t)b * Cc + ch0) * HWc + (size_t)w0 * Wc;
    float* outb = out + (((size_t)b * Cc + ch0) * Kc) * (size_t)HWc + spg;

    // stage-pair helpers: pair p = channels (2p, 2p+1); 2 float4 per thread
    // (TILE4=736 > NT=512: idx tid in plane0; tid+512 spans plane0 tail+plane1)
    auto LOADP = [&](int p, float4& a0, float4& a1) {
        const float4* f0 = (const float4*)(xw + (size_t)(2 * p) * HWc);
        const float4* f1 = (const float4*)(xw + (size_t)(2 * p + 1) * HWc);
        a0 = f0[tid];
        int i1 = tid + NT;
        a1 = (i1 < TILE4) ? f0[i1] : f1[i1 - TILE4];
        // remaining elements: i2 = tid + 1024 covers plane1 indices 288..1023
        // handled by third slot below
    };
    auto LOADP3 = [&](int p, float4& a2) {
        const float4* f1 = (const float4*)(xw + (size_t)(2 * p + 1) * HWc);
        int i2 = tid + 2 * NT;
        if (i2 < 2 * TILE4) a2 = f1[i2 - TILE4];
    };
    auto WRITEP = [&](int pb, float4 a0, float4 a1, float4 a2) {
        float4* d0 = (float4*)buf[pb][0];
        float4* d1 = (float4*)buf[pb][1];
        d0[tid] = a0;
        int i1 = tid + NT;
        if (i1 < TILE4) d0[i1] = a1; else d1[i1 - TILE4] = a1;
        int i2 = tid + 2 * NT;
        if (i2 < 2 * TILE4) d1[i2 - TILE4] = a2;
    };
    auto COMPUTE = [&](int pb, int p) {
        const float* B0 = buf[pb][0];
        const float* B1 = buf[pb][1];
        float* oc0 = outb + (size_t)(2 * p) * (Kc * HWc);
        float* oc1 = oc0 + (size_t)Kc * HWc;
        if (allok) {
#pragma unroll
            for (int k = 0; k < Kc; ++k) {
                int at = am[k] & 0xffff;
                int ab = am[k] >> 16;
                float t00 = B0[at], t01 = B0[at + 1];    // ds_read2
                float u00 = B0[ab], u01 = B0[ab + 1];
                float t10 = B1[at], t11 = B1[at + 1];
                float u10 = B1[ab], u11 = B1[ab + 1];
                float v0 = wyt[k] * (wA[k] * t00 + wB[k] * t01)
                         + wyb[k] * (wA[k] * u00 + wB[k] * u01);
                float v1 = wyt[k] * (wA[k] * t10 + wB[k] * t11)
                         + wyb[k] * (wA[k] * u10 + wB[k] * u11);
                __builtin_nontemporal_store(v0, &oc0[(size_t)k * HWc]);
                __builtin_nontemporal_store(v1, &oc1[(size_t)k * HWc]);
            }
        } else {
            // effectively-never: clamped sample row outside 23-row window
            const float* xc0 = x + ((size_t)b * Cc + ch0 + 2 * p) * HWc + w0 * Wc;
            const float* xc1 = xc0 + HWc;
#pragma unroll 1
            for (int k = 0; k < Kc; ++k) {
                int at = am[k] & 0xffff;
                int ab = am[k] >> 16;
                float t00 = xc0[at], t01 = xc0[at + 1];
                float u00 = xc0[ab], u01 = xc0[ab + 1];
                float t10 = xc1[at], t11 = xc1[at + 1];
                float u10 = xc1[ab], u11 = xc1[ab + 1];
                float v0 = wyt[k] * (wA[k] * t00 + wB[k] * t01)
                         + wyb[k] * (wA[k] * u00 + wB[k] * u01);
                float v1 = wyt[k] * (wA[k] * t10 + wB[k] * t11)
                         + wyb[k] * (wA[k] * u10 + wB[k] * u11);
                oc0[(size_t)k * HWc] = v0;
                oc1[(size_t)k * HWc] = v1;
            }
        }
    };

    // ---- prologue: stage pair 0, preload pair 1 ----
    float4 a0, a1, a2, n0, n1, n2;
    LOADP(0, a0, a1); LOADP3(0, a2);
    WRITEP(0, a0, a1, a2);
    LOADP(1, n0, n1); LOADP3(1, n2);
    __syncthreads();

    // ---- main pipeline: ONE barrier per pair ----
    for (int j = 0; j < PAIRS; ++j) {
        int pb = j & 1;
        if (j + 1 < PAIRS) WRITEP(pb ^ 1, n0, n1, n2);   // pair j+1 -> other buf
        if (j + 2 < PAIRS) { LOADP(j + 2, a0, a1); LOADP3(j + 2, a2); }
        COMPUTE(pb, j);
        __syncthreads();
        n0 = a0; n1 = a1; n2 = a2;
    }
}

extern "C" void kernel_launch(void* const* d_in, const int* in_sizes, int n_in,
                              void* d_out, int out_size, void* d_ws, size_t ws_size,
                              hipStream_t stream) {
    const float* x      = (const float*)d_in[0];
    const float* offset = (const float*)d_in[1];
    float* out          = (float*)d_out;

    int grid = Bc * (Hc / ORc) * (Cc / CPB);   // 8*32*4 = 1024 blocks
    deform_lds6<<<grid, NT, 0, stream>>>(x, offset, out);
}

// Round 10
// 64.497 us; speedup vs baseline: 2.1572x; 2.1572x over previous
//
#include <hip/hip_runtime.h>

// DeformUnfold R9 = exact R5 revert (proven 64.5 us).
// 1-barrier software pipeline, 2 channels/iter, nt stores.
// Block = (batch, 4-row quad, 32-ch half), 512 threads, 1 sp each.
// Iter j: ds_write pair j+1 (regs loaded in iter j-1) -> buf[p^1],
//         issue loads pair j+2, compute pair j from buf[p], ONE barrier.
// Sampling meta (channel-independent) in registers; x-pair remap so each tap
// row is one ds_read2_b32. Rare out-of-window lanes take a global slow path.
// Lessons encoded: MARG must stay 9 (R7: 6e-5 slow-path prob already costs
// 7 us); NEVER cap VGPR below ~110 (R6/R8: spill -> 2-3x regression).

constexpr int Bc = 8;
constexpr int Cc = 64;
constexpr int Hc = 128;
constexpr int Wc = 128;
constexpr int Kc = 9;
constexpr int HWc = 16384;
constexpr int ORc = 4;                // output rows per block
constexpr int ROWS = 23;              // staged window rows
constexpr int TILE = ROWS * Wc;       // 2944 floats
constexpr int TILE4 = TILE / 4;       // 736 float4
constexpr int CPB = 32;               // channels per block
constexpr int PAIRS = CPB / 2;        // 16 iterations
constexpr int MARG = 9;
constexpr int NT = 512;

__global__ __launch_bounds__(NT, 4) void deform_lds3(
    const float* __restrict__ x,
    const float* __restrict__ offset,
    float* __restrict__ out)
{
    __shared__ float buf[2][2][TILE];     // 46 KB: [phase][ch-of-pair][win]

    // XCD swizzle: batch b -> XCD b (x per batch ~4.2MB ~ one L2)
    int wg = (int)((blockIdx.x & 7) * 64 + (blockIdx.x >> 3));
    int h  = wg & 1;
    int rq = (wg >> 1) & 31;
    int b  = wg >> 6;

    int r0  = rq * ORc;
    int w0  = min(max(r0 - MARG, 0), Hc - ROWS);
    int tid = (int)threadIdx.x;
    int ho  = r0 + (tid >> 7);
    int wo  = tid & 127;
    int spg = r0 * Wc + tid;
    int ch0 = h * CPB;

    const float* offb = offset + (size_t)b * (2 * Kc) * HWc + spg;

    // ---- per-thread sampling meta (channel-independent) ----
    int   at[Kc], ab[Kc];
    float wA[Kc], wB[Kc], wyt[Kc], wyb[Kc];
    bool allok = true;
#pragma unroll
    for (int k = 0; k < Kc; ++k) {
        float offy = offb[(size_t)(2 * k) * HWc];
        float offx = offb[(size_t)(2 * k + 1) * HWc];
        float py = (float)(k / 3 + ho - 1) + offy;
        float px = (float)(k % 3 + wo - 1) + offx;
        float y0f = floorf(py), x0f = floorf(px);
        float ly = py - y0f, lx = px - x0f;
        float hy = 1.0f - ly, hx = 1.0f - lx;
        int y0 = (int)y0f, x0 = (int)x0f;
        int y1 = y0 + 1;

        bool vy0 = (unsigned)y0 < (unsigned)Hc;
        bool vy1 = (unsigned)y1 < (unsigned)Hc;
        wyt[k] = hy * (vy0 ? 1.0f : 0.0f);
        wyb[k] = ly * (vy1 ? 1.0f : 0.0f);

        int xb = min(max(x0, 0), Wc - 2);
        bool n  = (x0 == xb);
        bool lo = (x0 + 1 == xb);
        bool hi = (x0 == xb + 1);
        wA[k] = (n ? hx : 0.0f) + (lo ? lx : 0.0f);
        wB[k] = (n ? lx : 0.0f) + (hi ? hx : 0.0f);

        int y0c = min(max(y0, 0), Hc - 1);
        int y1c = min(max(y1, 0), Hc - 1);
        allok = allok & (y0c >= w0) & (y0c < w0 + ROWS)
                      & (y1c >= w0) & (y1c < w0 + ROWS);
        at[k] = (y0c - w0) * Wc + xb;
        ab[k] = (y1c - w0) * Wc + xb;
    }

    const float* xw = x + ((size_t)b * Cc + ch0) * HWc + (size_t)w0 * Wc;
    float* outb = out + (((size_t)b * Cc + ch0) * Kc) * (size_t)HWc + spg;

    // stage-pair helpers: pair p = channels (2p, 2p+1); 3 float4 per thread
    auto LOADP = [&](int p, float4& a0, float4& a1, float4& a2) {
        const float* s = xw + (size_t)(2 * p) * HWc;
        const float4* f0 = (const float4*)s;
        const float4* f1 = (const float4*)(s + HWc);
        a0 = f0[tid];                              // 0..511 -> plane0
        int i1 = tid + 512;                        // crosses plane boundary
        a1 = (i1 < TILE4) ? f0[i1] : f1[i1 - TILE4];
        int i2 = tid + 1024;                       // plane1 tail
        if (i2 < 2 * TILE4) a2 = f1[i2 - TILE4];
    };
    auto WRITEP = [&](int pb, float4 a0, float4 a1, float4 a2) {
        float4* d0 = (float4*)buf[pb][0];
        float4* d1 = (float4*)buf[pb][1];
        d0[tid] = a0;
        int i1 = tid + 512;
        if (i1 < TILE4) d0[i1] = a1; else d1[i1 - TILE4] = a1;
        int i2 = tid + 1024;
        if (i2 < 2 * TILE4) d1[i2 - TILE4] = a2;
    };
    auto COMPUTE = [&](int pb, int p) {
        const float* B0 = buf[pb][0];
        const float* B1 = buf[pb][1];
        float* oc0 = outb + (size_t)(2 * p) * (Kc * HWc);
        float* oc1 = oc0 + (size_t)Kc * HWc;
        if (allok) {
#pragma unroll
            for (int k = 0; k < Kc; ++k) {
                float t00 = B0[at[k]], t01 = B0[at[k] + 1];   // ds_read2
                float u00 = B0[ab[k]], u01 = B0[ab[k] + 1];
                float t10 = B1[at[k]], t11 = B1[at[k] + 1];
                float u10 = B1[ab[k]], u11 = B1[ab[k] + 1];
                float v0 = wyt[k] * (wA[k] * t00 + wB[k] * t01)
                         + wyb[k] * (wA[k] * u00 + wB[k] * u01);
                float v1 = wyt[k] * (wA[k] * t10 + wB[k] * t11)
                         + wyb[k] * (wA[k] * u10 + wB[k] * u11);
                __builtin_nontemporal_store(v0, &oc0[(size_t)k * HWc]);
                __builtin_nontemporal_store(v1, &oc1[(size_t)k * HWc]);
            }
        } else {
            // ultra-rare: clamped sample row outside staged window
            const float* xc0 = x + ((size_t)b * Cc + ch0 + 2 * p) * HWc + w0 * Wc;
            const float* xc1 = xc0 + HWc;
#pragma unroll 1
            for (int k = 0; k < Kc; ++k) {
                float t00 = xc0[at[k]], t01 = xc0[at[k] + 1];
                float u00 = xc0[ab[k]], u01 = xc0[ab[k] + 1];
                float t10 = xc1[at[k]], t11 = xc1[at[k] + 1];
                float u10 = xc1[ab[k]], u11 = xc1[ab[k] + 1];
                float v0 = wyt[k] * (wA[k] * t00 + wB[k] * t01)
                         + wyb[k] * (wA[k] * u00 + wB[k] * u01);
                float v1 = wyt[k] * (wA[k] * t10 + wB[k] * t11)
                         + wyb[k] * (wA[k] * u10 + wB[k] * u11);
                oc0[(size_t)k * HWc] = v0;
                oc1[(size_t)k * HWc] = v1;
            }
        }
    };

    // ---- prologue: stage pair 0, preload pair 1 ----
    float4 a0, a1, a2, n0, n1, n2;
    LOADP(0, a0, a1, a2);
    WRITEP(0, a0, a1, a2);
    LOADP(1, n0, n1, n2);
    __syncthreads();

    // ---- main pipeline: ONE barrier per pair ----
    for (int j = 0; j < PAIRS; ++j) {
        int pb = j & 1;
        if (j + 1 < PAIRS) WRITEP(pb ^ 1, n0, n1, n2);  // pair j+1 -> other buf
        if (j + 2 < PAIRS) LOADP(j + 2, a0, a1, a2);    // issue pair j+2
        COMPUTE(pb, j);
        __syncthreads();
        n0 = a0; n1 = a1; n2 = a2;
    }
}

extern "C" void kernel_launch(void* const* d_in, const int* in_sizes, int n_in,
                              void* d_out, int out_size, void* d_ws, size_t ws_size,
                              hipStream_t stream) {
    const float* x      = (const float*)d_in[0];
    const float* offset = (const float*)d_in[1];
    float* out          = (float*)d_out;

    int grid = Bc * (Hc / ORc) * (Cc / CPB);   // 512 blocks
    deform_lds3<<<grid, NT, 0, stream>>>(x, offset, out);
}